// Round 9
// baseline (295.051 us; speedup 1.0000x reference)
//
#include <hip/hip_runtime.h>

typedef __attribute__((ext_vector_type(8))) short short8;
typedef __attribute__((ext_vector_type(4))) short short4v;
typedef __attribute__((ext_vector_type(4))) float floatx4;

#define NSYM 20000

__device__ __forceinline__ unsigned short f2bf(float f) {
    unsigned int u = __float_as_uint(f);
    u += 0x7FFFu + ((u >> 16) & 1u);   // round-to-nearest-even
    return (unsigned short)(u >> 16);
}
__device__ __forceinline__ float bf2f(unsigned short s) {
    return __uint_as_float(((unsigned int)s) << 16);
}
__device__ __forceinline__ float sigmoidf(float x) {
    return 1.f / (1.f + __expf(-x));
}
__device__ __forceinline__ short4v pack4(floatx4 v) {
    short4v o;
    o[0] = (short)f2bf(v[0]); o[1] = (short)f2bf(v[1]);
    o[2] = (short)f2bf(v[2]); o[3] = (short)f2bf(v[3]);
    return o;
}

// Both weight halves -> bf16 MFMA A-operand fragments, K=256 each.
// half 0 (wswzP): W[d][k], k=0..255 (prev);  half 1 (wswzU): k=256..511 (upd).
// short8 idx = (g*8 + ks)*64 + lane; g<16 -> Wf cols g*16+l15, g>=16 -> Wa.
__global__ __launch_bounds__(256)
void convert_w_kernel(const float* __restrict__ Wf,
                      const float* __restrict__ Wa,
                      short* __restrict__ wswzP,
                      short* __restrict__ wswzU)
{
    int id = blockIdx.x * 256 + threadIdx.x;   // 32768 total
    int half = id >> 14;
    int rem  = id & 16383;
    int slot = rem & 63, ks = (rem >> 6) & 7, g = rem >> 9;
    int l15 = slot & 15, lk = slot >> 4;
    const float* wrow = ((g < 16) ? Wf : Wa) + (long)((g & 15) * 16 + l15) * 512;
    const float* src  = wrow + half * 256 + ks * 32 + lk * 8;
    floatx4 w0 = *(const floatx4*)src;
    floatx4 w1 = *(const floatx4*)(src + 4);
    short8 o;
    o[0] = (short)f2bf(w0[0]); o[1] = (short)f2bf(w0[1]);
    o[2] = (short)f2bf(w0[2]); o[3] = (short)f2bf(w0[3]);
    o[4] = (short)f2bf(w1[0]); o[5] = (short)f2bf(w1[1]);
    o[6] = (short)f2bf(w1[2]); o[7] = (short)f2bf(w1[3]);
    short* dst = half ? wswzU : wswzP;
    *(short8*)(dst + (long)((g * 8 + ks) * 64 + slot) * 8) = o;
}

__global__ __launch_bounds__(256)
void zero_flags_kernel(unsigned int* __restrict__ flags)   // 256 KB
{
    flags[blockIdx.x * 256 + threadIdx.x] = 0u;
}

__global__ __launch_bounds__(256)
void mark_kernel(const int* __restrict__ ei, const int* __restrict__ ti,
                 unsigned char* __restrict__ flags, int n)
{
    int i = blockIdx.x * 256 + threadIdx.x;
    if (i < n) flags[64 * ei[i] + ti[i]] = 1;
}

__global__ __launch_bounds__(256)
void copy_rest_kernel(const float* __restrict__ flat,
                      const unsigned char* __restrict__ flags,
                      float* __restrict__ out, int nrows)
{
    const int lane = threadIdx.x & 63;
    const int w0   = (blockIdx.x * 256 + threadIdx.x) >> 6;
    const int nw   = (gridDim.x * 256) >> 6;
    for (int row = w0; row < nrows; row += nw) {
        if (flags[row]) continue;
        const floatx4* s = (const floatx4*)(flat + (long)row * 256);
        floatx4*       o = (floatx4*)(out + (long)row * 256);
        o[lane] = s[lane];
    }
}

// Precompute symL[s][0..255]   = syms[s] @ Wf_upd^T + bf   (forget logit part)
//            symL[s][256..511] = syms[s] @ Wa_upd^T + ba   (add logit part)
// bf16 output. Tile = 64 symbol rows, 8 waves, K=256 MFMA, tail-guarded.
__global__ __launch_bounds__(512, 4)
void syms_logits_kernel(const float* __restrict__ syms,
                        const float* __restrict__ bfb,
                        const float* __restrict__ bab,
                        const short* __restrict__ wswzU,
                        short* __restrict__ symLg)
{
    __shared__ __align__(16) short S_lds[64 * 256];   // 32 KB
    const int tid = threadIdx.x;
    const int r0  = blockIdx.x * 64;
    {
        const int r = tid >> 3, se = tid & 7;
        const int s = min(r0 + r, NSYM - 1);
        const float* srow = syms + (long)s * 256;
        #pragma unroll
        for (int i = 0; i < 8; ++i) {
            const int gi = i * 8 + se;               // fp32 16B-granule 0..63
            floatx4 v = *(const floatx4*)(srow + gi * 4);
            const int cb = gi >> 1, hf = gi & 1;
            *(short4v*)&S_lds[r * 256 + ((cb ^ (r & 7)) << 3) + hf * 4] = pack4(v);
        }
    }
    __syncthreads();

    const int lane = tid & 63, w = tid >> 6, l15 = lane & 15, lk = lane >> 4;
    floatx4 acc[4][4];
    #pragma unroll
    for (int mi = 0; mi < 4; ++mi)
        #pragma unroll
        for (int c = 0; c < 4; ++c)
            acc[mi][c] = (floatx4){0.f, 0.f, 0.f, 0.f};

    const short8* wsv = (const short8*)wswzU;
    #pragma unroll
    for (int ks = 0; ks < 8; ++ks) {
        short8 cb[4];
        #pragma unroll
        for (int mi = 0; mi < 4; ++mi) {
            const int m  = mi * 16 + l15;
            const int ch = (ks * 4 + lk) ^ (m & 7);
            cb[mi] = *(const short8*)&S_lds[m * 256 + (ch << 3)];
        }
        #pragma unroll
        for (int c = 0; c < 4; ++c) {
            const int g = (c < 2) ? (w * 2 + c) : (16 + w * 2 + (c - 2));
            const short8 wf = wsv[(g * 8 + ks) * 64 + lane];
            #pragma unroll
            for (int mi = 0; mi < 4; ++mi)
                acc[mi][c] = __builtin_amdgcn_mfma_f32_16x16x32_bf16(
                    wf, cb[mi], acc[mi][c], 0, 0, 0);
        }
    }

    #pragma unroll
    for (int c = 0; c < 2; ++c) {
        const int d0 = w * 32 + c * 16 + lk * 4;
        const floatx4 bF = *(const floatx4*)(bfb + d0);
        const floatx4 bA = *(const floatx4*)(bab + d0);
        #pragma unroll
        for (int mi = 0; mi < 4; ++mi) {
            const int m = mi * 16 + l15;
            const int s = r0 + m;
            if (s < NSYM) {
                short4v oF, oA;
                #pragma unroll
                for (int j = 0; j < 4; ++j) {
                    oF[j] = (short)f2bf(acc[mi][c][j]     + bF[j]);
                    oA[j] = (short)f2bf(acc[mi][c + 2][j] + bA[j]);
                }
                *(short4v*)(symLg + (long)s * 512 + d0)       = oF;
                *(short4v*)(symLg + (long)s * 512 + 256 + d0) = oA;
            }
        }
    }
}

// Persistent fused kernel: 8 tiles/block, 32 occ rows/tile, 512 thr (8 waves).
// LDS 64KB: prev bf16 [0,8192), upd bf16 [8192,16384), symL bf16 [16384,32768)
// (short indices), all chunk^=(row&7) swizzled.
// Per tile: ds_write staged regs -> barrier -> PREFETCH next tile's gather
// into regs (flies under GEMM) -> K=256 MFMA (weights streamed from L2,
// acc[2][4]) -> barrier -> combine in-LDS (logit = acc + symL; gates; bf16
// into prev slots) -> barrier -> full-row dwordx4 stores (no write-allocate).
__global__ __launch_bounds__(512, 4)
void main_kernel(const float* __restrict__ flat,   // [262144,256]
                 const float* __restrict__ syms,   // [20000,256]
                 const int* __restrict__ ei,
                 const int* __restrict__ ti,
                 const int* __restrict__ si,
                 const short* __restrict__ wswzP,
                 const short* __restrict__ symLg,
                 float* __restrict__ out)
{
    __shared__ __align__(16) short L[32768];   // 64 KB

    const int tid  = threadIdx.x;
    const int lane = tid & 63, w = tid >> 6, l15 = lane & 15, lk = lane >> 4;
    const int r = tid >> 4, se = tid & 15;     // staging: 16 thr/row, 32 rows
    const int base_occ = blockIdx.x * 256;     // 8 tiles x 32

    floatx4 pv[4], uv[4];
    short8  sl[4];
    auto issue = [&](int occ0) {
        const int occ = occ0 + r;
        const long rowp = 64 * ei[occ] + ti[occ];
        const long syr  = si[occ];
        const float* pr = flat + rowp * 256;
        const float* ur = syms + syr * 256;
        const short* lr = symLg + syr * 512;
        #pragma unroll
        for (int i = 0; i < 4; ++i) {
            const int gi = i * 16 + se;
            pv[i] = *(const floatx4*)(pr + gi * 4);
            uv[i] = *(const floatx4*)(ur + gi * 4);
            sl[i] = *(const short8*)(lr + gi * 8);
        }
    };

    issue(base_occ);

    const short8* wsv = (const short8*)wswzP;

    #pragma unroll
    for (int t = 0; t < 8; ++t) {
        const int occ0 = base_occ + t * 32;
        if (t) __syncthreads();                       // (a) store-phase done
        // ---- ds_write staged tile (conflict-free swizzled) ----
        #pragma unroll
        for (int i = 0; i < 4; ++i) {
            const int gi = i * 16 + se;
            const int cb = gi >> 1, hf = gi & 1;
            const int so = ((cb ^ (r & 7)) << 3) + hf * 4;
            *(short4v*)&L[r * 256 + so]        = pack4(pv[i]);
            *(short4v*)&L[8192 + r * 256 + so] = pack4(uv[i]);
            *(short8*)&L[16384 + r * 512 + ((gi ^ (r & 7)) << 3)] = sl[i];
        }
        __syncthreads();                              // (b) tile ready

        if (t < 7) issue(occ0 + 32);                  // prefetch under GEMM

        // ---- K=256 MFMA: A=weights (L2 stream), B=prev rows (LDS) ----
        floatx4 acc[2][4];                            // [mi][c:0,1=F 2,3=A]
        #pragma unroll
        for (int mi = 0; mi < 2; ++mi)
            #pragma unroll
            for (int c = 0; c < 4; ++c)
                acc[mi][c] = (floatx4){0.f, 0.f, 0.f, 0.f};

        #pragma unroll
        for (int ks = 0; ks < 8; ++ks) {
            short8 cb2[2];
            #pragma unroll
            for (int mi = 0; mi < 2; ++mi) {
                const int m  = mi * 16 + l15;
                const int ch = (ks * 4 + lk) ^ (m & 7);
                cb2[mi] = *(const short8*)&L[m * 256 + (ch << 3)];
            }
            #pragma unroll
            for (int c = 0; c < 4; ++c) {
                const int g = (c < 2) ? (2 * w + c) : (16 + 2 * w + (c - 2));
                const short8 wf = wsv[(g * 8 + ks) * 64 + lane];
                acc[0][c] = __builtin_amdgcn_mfma_f32_16x16x32_bf16(
                    wf, cb2[0], acc[0][c], 0, 0, 0);
                acc[1][c] = __builtin_amdgcn_mfma_f32_16x16x32_bf16(
                    wf, cb2[1], acc[1][c], 0, 0, 0);
            }
        }
        __syncthreads();                              // (c) GEMM reads done

        // ---- combine: lane owns (m, d0..d0+3), cc=0,1 d-subtiles ----
        #pragma unroll
        for (int cc = 0; cc < 2; ++cc) {
            const int d0  = (2 * w + cc) * 16 + lk * 4;
            const int pch = d0 >> 3;
            const int ps  = d0 & 7;                   // 0 or 4
            #pragma unroll
            for (int mi = 0; mi < 2; ++mi) {
                const int m = mi * 16 + l15, sw = m & 7;
                const int slot = ((pch ^ sw) << 3) + ps;
                short4v pvv = *(const short4v*)&L[m * 256 + slot];
                short4v uvv = *(const short4v*)&L[8192 + m * 256 + slot];
                short4v sF  = *(const short4v*)&L[16384 + m * 512 + slot];
                short4v sA  = *(const short4v*)&L[16384 + m * 512 +
                                                  (((32 + pch) ^ sw) << 3) + ps];
                short4v o;
                #pragma unroll
                for (int j = 0; j < 4; ++j) {
                    float fg = sigmoidf(acc[mi][cc][j]     + bf2f((unsigned short)sF[j]));
                    float ag = sigmoidf(acc[mi][2 + cc][j] + bf2f((unsigned short)sA[j]));
                    o[j] = (short)f2bf(fg * bf2f((unsigned short)pvv[j])
                                     + ag * bf2f((unsigned short)uvv[j]));
                }
                *(short4v*)&L[m * 256 + slot] = o;
            }
        }
        __syncthreads();                              // (d) combined ready

        // ---- full-row stores: wave w -> rows w*4..w*4+3 ----
        #pragma unroll
        for (int i = 0; i < 4; ++i) {
            const int rr  = w * 4 + i;
            const int occ = occ0 + rr;
            const long orow = 64 * ei[occ] + ti[occ];
            short4v sv = *(const short4v*)
                &L[rr * 256 + (((lane >> 1) ^ (rr & 7)) << 3) + (lane & 1) * 4];
            floatx4 o4;
            o4[0] = bf2f((unsigned short)sv[0]);
            o4[1] = bf2f((unsigned short)sv[1]);
            o4[2] = bf2f((unsigned short)sv[2]);
            o4[3] = bf2f((unsigned short)sv[3]);
            *(floatx4*)(out + orow * 256 + lane * 4) = o4;
        }
    }
}

extern "C" void kernel_launch(void* const* d_in, const int* in_sizes, int n_in,
                              void* d_out, int out_size, void* d_ws, size_t ws_size,
                              hipStream_t stream) {
    const float* flat = (const float*)d_in[0];
    const float* syms = (const float*)d_in[1];
    const float* Wf   = (const float*)d_in[2];
    const float* bf   = (const float*)d_in[3];
    const float* Wa   = (const float*)d_in[4];
    const float* ba   = (const float*)d_in[5];
    const int* ei     = (const int*)d_in[6];
    const int* ti     = (const int*)d_in[7];
    const int* si     = (const int*)d_in[8];
    float* out        = (float*)d_out;

    short* wswzP         = (short*)d_ws;                          // 256 KB
    short* wswzU         = (short*)d_ws + 131072;                 // 256 KB
    unsigned char* flags = (unsigned char*)d_ws + 524288;         // 256 KB
    short* symLg         = (short*)((char*)d_ws + 786432);        // 20.5 MB

    const int n_occ = in_sizes[6];        // 131072
    const int nrows = out_size / 256;     // 262144

    zero_flags_kernel<<<nrows / 1024, 256, 0, stream>>>((unsigned int*)flags);
    mark_kernel<<<(n_occ + 255) / 256, 256, 0, stream>>>(ei, ti, flags, n_occ);
    convert_w_kernel<<<128, 256, 0, stream>>>(Wf, Wa, wswzP, wswzU);
    syms_logits_kernel<<<(NSYM + 63) / 64, 512, 0, stream>>>(syms, bf, ba,
                                                             wswzU, symLg);

    main_kernel<<<n_occ / 256, 512, 0, stream>>>(flat, syms, ei, ti, si,
                                                 wswzP, symLg, out);

    copy_rest_kernel<<<2048, 256, 0, stream>>>(flat, flags, out, nrows);
}